// Round 4
// baseline (383.672 us; speedup 1.0000x reference)
//
#include <hip/hip_runtime.h>
#include <math.h>

// Problem constants (from reference):
//   B = 16384 rows, N = 4096 cols, CELL_SIZES = trunc(linspace(2,100,10))
#define N_COLS 4096
#define WIN 200            // 2 * max cell size
#define CENTER 100

// Scan one 1024-elem quarter held in v[4] (float4 per lane, 4 chunks of 256).
// Returns wave-reduced (bestv, besti) with strict-local-max + min-index tie-break.
__device__ __forceinline__ void scan_quarter(
    const float4* __restrict__ v, int base, int lane, float seamL, float seamR,
    float& bestv, int& besti)
{
    bestv = -INFINITY; besti = 0;
    #pragma unroll
    for (int c = 0; c < 4; ++c) {
        const int p = base + c * 256 + lane * 4;
        const float4 cc = v[c];

        float left  = __shfl_up(cc.w, 1, 64);
        float right = __shfl_down(cc.x, 1, 64);
        if (c > 0) { const float e0 = __shfl(v[c - 1].w, 63, 64); if (lane == 0)  left  = e0; }
        else       { if (lane == 0)  left  = seamL; }
        if (c < 3) { const float e1 = __shfl(v[c + 1].x, 0, 64);  if (lane == 63) right = e1; }
        else       { if (lane == 63) right = seamR; }
        // (p==0): left unused due to p>=1 guard. (p+3==N-1): right unused via guard.

        if (p >= 1 && cc.x > left && cc.x > cc.y && cc.x > bestv) { bestv = cc.x; besti = p; }
        if (cc.y > cc.x && cc.y > cc.z && cc.y > bestv)           { bestv = cc.y; besti = p + 1; }
        if (cc.z > cc.y && cc.z > cc.w && cc.z > bestv)           { bestv = cc.z; besti = p + 2; }
        if (p + 3 <= N_COLS - 2 && cc.w > cc.z && cc.w > right && cc.w > bestv) {
            bestv = cc.w; besti = p + 3;
        }
    }
    #pragma unroll
    for (int off = 32; off >= 1; off >>= 1) {
        const float ov = __shfl_xor(bestv, off, 64);
        const int   oi = __shfl_xor(besti, off, 64);
        if (ov > bestv || (ov == bestv && oi < besti)) { bestv = ov; besti = oi; }
    }
}

// Kernel A: pure streaming peak-argmax. Block handles TWO rows; all 8 dwordx4
// loads per lane issue before any dependent compute -> 32 KB in flight/block.
__global__ __launch_bounds__(256) void peak_kernel(
    const float* __restrict__ inp,   // [B, N]
    int* __restrict__ top1,          // [B] (in d_ws)
    int B)
{
    const int wave = threadIdx.x >> 6;
    const int lane = threadIdx.x & 63;
    const int r0   = blockIdx.x * 2;
    if (r0 >= B) return;

    const float* __restrict__ xA = inp + (size_t)r0 * N_COLS;
    const float* __restrict__ xB = xA + N_COLS;     // B is even (16384)

    __shared__ float s_bv[2][4];
    __shared__ int   s_bi[2][4];

    const int base = wave * 1024;

    float4 va[4], vb[4];
    #pragma unroll
    for (int c = 0; c < 4; ++c)
        va[c] = *reinterpret_cast<const float4*>(xA + base + c * 256 + lane * 4);
    #pragma unroll
    for (int c = 0; c < 4; ++c)
        vb[c] = *reinterpret_cast<const float4*>(xB + base + c * 256 + lane * 4);

    float seamLA = 0.f, seamRA = 0.f, seamLB = 0.f, seamRB = 0.f;
    if (lane == 0 && base > 0) {
        seamLA = xA[base - 1]; seamLB = xB[base - 1];
    }
    if (lane == 63 && base + 1024 < N_COLS) {
        seamRA = xA[base + 1024]; seamRB = xB[base + 1024];
    }

    float bv; int bi;
    scan_quarter(va, base, lane, seamLA, seamRA, bv, bi);
    if (lane == 0) { s_bv[0][wave] = bv; s_bi[0][wave] = bi; }
    scan_quarter(vb, base, lane, seamLB, seamRB, bv, bi);
    if (lane == 0) { s_bv[1][wave] = bv; s_bi[1][wave] = bi; }
    __syncthreads();

    // waves cover ascending disjoint ranges; min-index tie-break
    if (threadIdx.x == 0 || threadIdx.x == 64) {
        const int r = threadIdx.x >> 6;          // 0 -> row r0, 1 -> row r0+1
        float v0 = s_bv[r][0]; int i0 = s_bi[r][0];
        #pragma unroll
        for (int k = 1; k < 4; ++k) {
            const float ov = s_bv[r][k]; const int oi = s_bi[r][k];
            if (ov > v0 || (ov == v0 && oi < i0)) { v0 = ov; i0 = oi; }
        }
        top1[r0 + r] = i0;                        // ==0 if no peak (argmax of all -inf)
    }
}

// Kernel B: 200-wide circular window + 10 nested softmax features + linear+relu.
// Wave per row. Softmax without max-subtraction (shift-invariant; |x|<=~6 -> safe).
__global__ __launch_bounds__(256) void window_kernel(
    const float* __restrict__ inp,   // [B, N]
    const float* __restrict__ ss,    // [N]
    const float* __restrict__ wt,    // [1, 10]
    const float* __restrict__ bias,  // [1]
    const int* __restrict__ top1,    // [B]
    float* __restrict__ out,         // [B, 1]
    int B)
{
    const int wave = threadIdx.x >> 6;
    const int lane = threadIdx.x & 63;
    const int row  = blockIdx.x * 4 + wave;
    if (row >= B) return;

    const float* __restrict__ x = inp + (size_t)row * N_COLS;
    const int t1 = top1[row];

    float e[4], t[4];
    #pragma unroll
    for (int q = 0; q < 4; ++q) {
        const int j = lane + q * 64;
        const int pos = (t1 - CENTER + j) & (N_COLS - 1);
        const float xv = x[pos];
        const float sv = ss[pos];
        e[q] = (j < WIN) ? __expf(xv) : 0.0f;
        t[q] = e[q] * sv;
    }

    const int cells[10] = {2, 12, 23, 34, 45, 56, 67, 78, 89, 100};
    float acc = 0.0f;
    #pragma unroll
    for (int f = 0; f < 10; ++f) {
        const int lo = CENTER - cells[f];
        const int hi = CENTER + cells[f];
        float s1 = 0.0f, s2 = 0.0f;
        #pragma unroll
        for (int q = 0; q < 4; ++q) {
            const int j = lane + q * 64;
            if (j >= lo && j < hi) { s1 += e[q]; s2 += t[q]; }
        }
        #pragma unroll
        for (int off = 32; off >= 1; off >>= 1) {
            s1 += __shfl_xor(s1, off, 64);
            s2 += __shfl_xor(s2, off, 64);
        }
        acc += (s2 / s1) * wt[f];
    }

    if (lane == 0) {
        const float r = acc + bias[0];
        out[row] = r > 0.0f ? r : 0.0f;
    }
}

extern "C" void kernel_launch(void* const* d_in, const int* in_sizes, int n_in,
                              void* d_out, int out_size, void* d_ws, size_t ws_size,
                              hipStream_t stream) {
    const float* inp  = (const float*)d_in[0];   // [B, 4096]
    const float* ss   = (const float*)d_in[1];   // [4096]
    const float* wt   = (const float*)d_in[2];   // [1, 10]
    const float* bias = (const float*)d_in[3];   // [1]
    float* out = (float*)d_out;                  // [B, 1]
    int* top1 = (int*)d_ws;                      // [B] scratch (>= 64 KB available)

    const int B = in_sizes[0] / N_COLS;
    peak_kernel<<<(B + 1) / 2, 256, 0, stream>>>(inp, top1, B);
    window_kernel<<<(B + 3) / 4, 256, 0, stream>>>(inp, ss, wt, bias, top1, out, B);
}